// Round 2
// baseline (818.033 us; speedup 1.0000x reference)
//
#include <hip/hip_runtime.h>

// DCRNN (DCE'd): 65536 independent sequences, 12 steps, 2-layer GRU-lite, H=64.
// fp32 vector-ALU implementation (no fp32 MFMA on CDNA4).
//
// Block: 256 threads, 64 sequences. Thread tile: 4 seqs (TM) x 4 cols (TN),
// computing both u and c gates (32 accumulators). A-matrix [64][h0|h1] in LDS,
// row stride 132 floats (pad -> 2-way bank aliasing = free). Weights packed in
// d_ws as float4-per-(4k,col) and read from global (L1/L2 broadcast).

#define TSTEPS 12
#define SEQ 64
#define AROW 132

__device__ __forceinline__ float fsig(float z) {
    z = fminf(fmaxf(z, -30.f), 30.f);
    return 1.f / (1.f + __expf(-z));
}
__device__ __forceinline__ float ftanh(float z) {
    z = fminf(fmaxf(z, -15.f), 15.f);
    float e = __expf(2.f * z);
    return 1.f - 2.f / (e + 1.f);
}

// ---- workspace layout (floats) ----
// [0, 256)        W0x   : 64 float4  (Wu0[0][c], Wu0[1][c], Wc0[0][c], Wc0[1][c])
// [256, 8448)     W0h   : 16*128 float4  [k4][col<64 ? u : c] rows 2+4k4..
// [8448, 24832)   W1h   : 32*128 float4  [k4][col<64 ? u : c] rows 4k4..
// [24832, 24960)  bUC0  : bu0 | bc0
// [24960, 25088)  bUC1  : bu1 | bc1
// [25088, 25152)  Wo    : 64
// [25152]         bo

__global__ void pack_weights(const float* __restrict__ Wu0, const float* __restrict__ bu0,
                             const float* __restrict__ Wc0, const float* __restrict__ bc0,
                             const float* __restrict__ Wu1, const float* __restrict__ bu1,
                             const float* __restrict__ Wc1, const float* __restrict__ bc1,
                             const float* __restrict__ Wo, const float* __restrict__ bo,
                             float* __restrict__ Wp) {
    const int tid = blockIdx.x * blockDim.x + threadIdx.x;
    const int nthr = gridDim.x * blockDim.x;
    float4* W0x = (float4*)Wp;
    float4* W0h = (float4*)(Wp + 256);
    float4* W1h = (float4*)(Wp + 8448);

    if (tid < 64) {
        W0x[tid] = make_float4(Wu0[tid], Wu0[64 + tid], Wc0[tid], Wc0[64 + tid]);
    }
    for (int i = tid; i < 16 * 128; i += nthr) {
        const int k4 = i >> 7, col = i & 127;
        const float* G = (col < 64) ? Wu0 : Wc0;
        const int cc = col & 63;
        const int r = 2 + k4 * 4;
        W0h[i] = make_float4(G[r * 64 + cc], G[(r + 1) * 64 + cc],
                             G[(r + 2) * 64 + cc], G[(r + 3) * 64 + cc]);
    }
    for (int i = tid; i < 32 * 128; i += nthr) {
        const int k4 = i >> 7, col = i & 127;
        const float* G = (col < 64) ? Wu1 : Wc1;
        const int cc = col & 63;
        const int r = k4 * 4;
        W1h[i] = make_float4(G[r * 64 + cc], G[(r + 1) * 64 + cc],
                             G[(r + 2) * 64 + cc], G[(r + 3) * 64 + cc]);
    }
    if (tid < 128) Wp[24832 + tid] = (tid < 64) ? bu0[tid] : bc0[tid - 64];
    if (tid >= 128 && tid < 256) {
        const int q = tid - 128;
        Wp[24960 + q] = (q < 64) ? bu1[q] : bc1[q - 64];
    }
    if (tid >= 256 && tid < 320) Wp[25088 + (tid - 256)] = Wo[tid - 256];
    if (tid == 320) Wp[25152] = bo[0];
}

__global__ __launch_bounds__(256, 4) void dcrnn_main(const float* __restrict__ x,
                                                     const float* __restrict__ Wp,
                                                     float* __restrict__ out) {
    __shared__ float A[SEQ * AROW];   // [seq][0..63]=h0, [64..127]=h1, pad
    __shared__ float xs[SEQ * 2];

    const int tid = threadIdx.x;
    const int sg = tid & 15;        // seq group: seqs sg, sg+16, sg+32, sg+48
    const int jg = tid >> 4;        // col group 0..15
    const int jcol = jg * 4;

    const int s0 = blockIdx.x * SEQ;
    const int b = s0 >> 11;
    const int n0 = s0 & 2047;

    const float4* W0x = (const float4*)Wp;
    const float4* W0h = (const float4*)(Wp + 256);
    const float4* W1h = (const float4*)(Wp + 8448);

    const float4 bu0 = *(const float4*)(Wp + 24832 + jcol);
    const float4 bc0 = *(const float4*)(Wp + 24832 + 64 + jcol);
    const float4 bu1 = *(const float4*)(Wp + 24960 + jcol);
    const float4 bc1 = *(const float4*)(Wp + 24960 + 64 + jcol);

    for (int i = tid; i < SEQ * AROW; i += 256) A[i] = 0.f;

    const float* xb = x + (size_t)(b * TSTEPS) * 4096 + (size_t)n0 * 2;

    int srow[4];
#pragma unroll
    for (int m = 0; m < 4; ++m) srow[m] = (sg + 16 * m) * AROW;

#pragma unroll 1
    for (int t = 0; t < TSTEPS; ++t) {
        if (tid < 32) ((float4*)xs)[tid] = ((const float4*)(xb + t * 4096))[tid];
        __syncthreads();  // (1) x staged, h writes of prev step visible

        // ================= layer 0 : [x|h0] @ {Wu0,Wc0} =================
        float aU[4][4], aC[4][4];
#pragma unroll
        for (int m = 0; m < 4; ++m) {
            aU[m][0] = bu0.x; aU[m][1] = bu0.y; aU[m][2] = bu0.z; aU[m][3] = bu0.w;
            aC[m][0] = bc0.x; aC[m][1] = bc0.y; aC[m][2] = bc0.z; aC[m][3] = bc0.w;
        }
        {
            float4 wx[4];
#pragma unroll
            for (int j = 0; j < 4; ++j) wx[j] = W0x[jcol + j];
#pragma unroll
            for (int m = 0; m < 4; ++m) {
                const int s = sg + 16 * m;
                const float x0v = xs[2 * s], x1v = xs[2 * s + 1];
#pragma unroll
                for (int j = 0; j < 4; ++j) {
                    aU[m][j] += x0v * wx[j].x + x1v * wx[j].y;
                    aC[m][j] += x0v * wx[j].z + x1v * wx[j].w;
                }
            }
        }
#pragma unroll 2
        for (int k4 = 0; k4 < 16; ++k4) {
            float4 a4[4], wu[4], wc[4];
#pragma unroll
            for (int m = 0; m < 4; ++m) a4[m] = *(const float4*)&A[srow[m] + k4 * 4];
            const float4* wrow = &W0h[k4 * 128];
#pragma unroll
            for (int j = 0; j < 4; ++j) { wu[j] = wrow[jcol + j]; wc[j] = wrow[64 + jcol + j]; }
#pragma unroll
            for (int m = 0; m < 4; ++m)
#pragma unroll
                for (int j = 0; j < 4; ++j) {
                    aU[m][j] += a4[m].x * wu[j].x; aU[m][j] += a4[m].y * wu[j].y;
                    aU[m][j] += a4[m].z * wu[j].z; aU[m][j] += a4[m].w * wu[j].w;
                    aC[m][j] += a4[m].x * wc[j].x; aC[m][j] += a4[m].y * wc[j].y;
                    aC[m][j] += a4[m].z * wc[j].z; aC[m][j] += a4[m].w * wc[j].w;
                }
        }
        float4 hn[4];
#pragma unroll
        for (int m = 0; m < 4; ++m) {
            float4 hold = *(const float4*)&A[srow[m] + jcol];
            float* hp = (float*)&hold;
            float* hq = (float*)&hn[m];
#pragma unroll
            for (int j = 0; j < 4; ++j) {
                const float u = fsig(aU[m][j]);
                const float c = ftanh(aC[m][j]);
                hq[j] = u * hp[j] + (1.f - u) * c;
            }
        }
        __syncthreads();  // (2) all reads of h0_old done
#pragma unroll
        for (int m = 0; m < 4; ++m) *(float4*)&A[srow[m] + jcol] = hn[m];
        __syncthreads();  // (3) h0_new visible

        // ================= layer 1 : [h0|h1] @ {Wu1,Wc1} =================
#pragma unroll
        for (int m = 0; m < 4; ++m) {
            aU[m][0] = bu1.x; aU[m][1] = bu1.y; aU[m][2] = bu1.z; aU[m][3] = bu1.w;
            aC[m][0] = bc1.x; aC[m][1] = bc1.y; aC[m][2] = bc1.z; aC[m][3] = bc1.w;
        }
#pragma unroll 2
        for (int k4 = 0; k4 < 32; ++k4) {
            float4 a4[4], wu[4], wc[4];
#pragma unroll
            for (int m = 0; m < 4; ++m) a4[m] = *(const float4*)&A[srow[m] + k4 * 4];
            const float4* wrow = &W1h[k4 * 128];
#pragma unroll
            for (int j = 0; j < 4; ++j) { wu[j] = wrow[jcol + j]; wc[j] = wrow[64 + jcol + j]; }
#pragma unroll
            for (int m = 0; m < 4; ++m)
#pragma unroll
                for (int j = 0; j < 4; ++j) {
                    aU[m][j] += a4[m].x * wu[j].x; aU[m][j] += a4[m].y * wu[j].y;
                    aU[m][j] += a4[m].z * wu[j].z; aU[m][j] += a4[m].w * wu[j].w;
                    aC[m][j] += a4[m].x * wc[j].x; aC[m][j] += a4[m].y * wc[j].y;
                    aC[m][j] += a4[m].z * wc[j].z; aC[m][j] += a4[m].w * wc[j].w;
                }
        }
#pragma unroll
        for (int m = 0; m < 4; ++m) {
            float4 hold = *(const float4*)&A[srow[m] + 64 + jcol];
            float* hp = (float*)&hold;
            float* hq = (float*)&hn[m];
#pragma unroll
            for (int j = 0; j < 4; ++j) {
                const float u = fsig(aU[m][j]);
                const float c = ftanh(aC[m][j]);
                hq[j] = u * hp[j] + (1.f - u) * c;
            }
        }
        __syncthreads();  // (4) all reads of h1_old done
#pragma unroll
        for (int m = 0; m < 4; ++m) *(float4*)&A[srow[m] + 64 + jcol] = hn[m];
        // next-iteration barrier (1) makes h1_new visible before anyone reads it
    }

    __syncthreads();  // h1 final visible
    if (tid < 64) {
        const float4* WoP = (const float4*)(Wp + 25088);
        float acc = Wp[25152];
#pragma unroll
        for (int k4 = 0; k4 < 16; ++k4) {
            const float4 h4 = *(const float4*)&A[tid * AROW + 64 + k4 * 4];
            const float4 w4 = WoP[k4];
            acc += h4.x * w4.x + h4.y * w4.y + h4.z * w4.z + h4.w * w4.w;
        }
        out[s0 + tid] = acc;
    }
}

extern "C" void kernel_launch(void* const* d_in, const int* in_sizes, int n_in,
                              void* d_out, int out_size, void* d_ws, size_t ws_size,
                              hipStream_t stream) {
    const float* x   = (const float*)d_in[0];
    // d_in[1] supports, d_in[2] Wr0, d_in[3] br0 : dead code in reference
    const float* Wu0 = (const float*)d_in[4];
    const float* bu0 = (const float*)d_in[5];
    const float* Wc0 = (const float*)d_in[6];
    const float* bc0 = (const float*)d_in[7];
    // d_in[8] Wd0, d_in[9] bd0, d_in[10] Wr1, d_in[11] br1 : dead
    const float* Wu1 = (const float*)d_in[12];
    const float* bu1 = (const float*)d_in[13];
    const float* Wc1 = (const float*)d_in[14];
    const float* bc1 = (const float*)d_in[15];
    // d_in[16] Wd1, d_in[17] bd1 : dead
    const float* Wo  = (const float*)d_in[18];
    const float* bo  = (const float*)d_in[19];

    float* Wp = (float*)d_ws;  // needs ~101 KB

    hipLaunchKernelGGL(pack_weights, dim3(2), dim3(256), 0, stream,
                       Wu0, bu0, Wc0, bc0, Wu1, bu1, Wc1, bc1, Wo, bo, Wp);
    hipLaunchKernelGGL(dcrnn_main, dim3(65536 / SEQ), dim3(256), 0, stream,
                       x, Wp, (float*)d_out);
}